// Round 10
// baseline (34.202 us; speedup 1.0000x reference)
//
#include <hip/hip_runtime.h>

// GTCNN — 4-kernel structure; round-10 change: ALL wave-uniform LDS broadcasts
// replaced by register-slice + v_readlane (compile-time lane index => pure
// VALU, no DS-pipe traffic). Round 9 was LDS-pipe-bound (~210 DS instr/wave
// in spatial, ~12cy each shared per CU).
//
// Math (verified rounds 2-9): Adj = s0 I + s1 (I⊗As) + s2 (At⊗I) + s3 (At⊗As)
//   per layer: w[t] = sum_u At[t,u] h[u]   (temporal, per (b,n) column)
//              u = s1 h + s3 w ; p = s0 h + s2 w
//              Ah[m] = p[m] + sum_n As[m,n] u[n]   (spatial, per (b,t))
//              h' = tanh(Ah @ Hsum[l]),  Hsum[l] = sum_k H[l,k]
// Kernels: T0 = proj+temporal ; S0 = spatial+filter -> hbuf(n-major) ;
//          T1 = temporal ; S1 = spatial+filter+out-proj.
// Lane-distinct LDS tiles (At, x, As, Ah, T) keep the XOR group swizzle
// g' = g ^ (row&7) (b128 conflict-ideal, HW-proven rounds 6-9).
// Layouts: x[B][T*N][32]; up/pp[B][T][N][32]; hbuf[B][N][T][32]; out[B][T*N][16].

__device__ __forceinline__ int swz(int row, int g) { return g ^ (row & 7); }

__device__ __forceinline__ float rlane(float v, int lane) {
    return __builtin_bit_cast(float, __builtin_amdgcn_readlane(__builtin_bit_cast(int, v), lane));
}

// ---------------------------------------------------------------------------
// Temporal kernel. grid = B*N = 256, 512 threads.
// wave fg = tid>>6 (4-float f-chunk), lane lt = tid&63 (time step t AND slice
// slot u: lane u holds h[u][fg-chunk] in registers h0..h3).
// ---------------------------------------------------------------------------
template<bool PROJ>
__global__ __launch_bounds__(512) void k_temporal(
    const float* __restrict__ src,     // PROJ ? x : hbuf (n-major)
    const float* __restrict__ At,
    const float* __restrict__ W1, const float* __restrict__ b1,
    const float* __restrict__ s,
    float* __restrict__ up, float* __restrict__ pp)
{
    __shared__ float At_s[64 * 64];   // swizzled, b128 lane-distinct reads
    __shared__ float xs  [64 * 32];   // swizzled (PROJ only)

    const int tid = threadIdx.x;
    const int b   = blockIdx.x >> 7;
    const int n   = blockIdx.x & 127;
    const int fg  = tid >> 6;
    const int lt  = tid & 63;

    const float s0v = s[0], s1v = s[1], s2v = s[2], s3v = s[3];

    // stage At [64][64] -> swizzled groups
#pragma unroll
    for (int i = 0; i < 8; ++i) {
        int p = tid + 512 * i;
        int r = p >> 6, c = p & 63;
        At_s[r * 64 + (swz(r, c >> 2) << 2) + (c & 3)] = At[p];
    }

    float h0, h1, h2, h3;
    if (PROJ) {
        // stage x rows x[b, t*128+n, :] -> xs (swizzled, lane-distinct t rows)
        {
            int tt = tid >> 3, c4 = tid & 7;
            float4 v = *(const float4*)(src + ((size_t)(b * 8192 + tt * 128 + n)) * 32 + c4 * 4);
            *(float4*)&xs[tt * 32 + (swz(tt, c4) << 2)] = v;
        }
        // W1 register slice: lane l holds W1[k = l&31][fg*4..+4]
        float4 w1r = *(const float4*)(W1 + (lt & 31) * 32 + fg * 4);
        float4 bv  = *(const float4*)(b1 + fg * 4);
        __syncthreads();
        // h = x @ W1 + b1 : xs b128 lane-distinct + readlane W1
        h0 = bv.x; h1 = bv.y; h2 = bv.z; h3 = bv.w;
#pragma unroll
        for (int k4 = 0; k4 < 8; ++k4) {
            float4 xv = *(const float4*)&xs[lt * 32 + (swz(lt, k4) << 2)];
#define PROJSTEP(a, k)                                   \
            h0 += (a) * rlane(w1r.x, (k));               \
            h1 += (a) * rlane(w1r.y, (k));               \
            h2 += (a) * rlane(w1r.z, (k));               \
            h3 += (a) * rlane(w1r.w, (k));
            PROJSTEP(xv.x, k4 * 4 + 0)
            PROJSTEP(xv.y, k4 * 4 + 1)
            PROJSTEP(xv.z, k4 * 4 + 2)
            PROJSTEP(xv.w, k4 * 4 + 3)
        }
        // lane t computed h[t][fg-chunk] == slice slot the mix needs (u=lane).
    } else {
        // h register slice straight from hbuf (n-major row is contiguous 8KB)
        float4 hv = *(const float4*)(src + (((size_t)(b * 128 + n)) * 64 + lt) * 32 + fg * 4);
        h0 = hv.x; h1 = hv.y; h2 = hv.z; h3 = hv.w;
        __syncthreads();                       // At_s ready
    }

    // temporal mix: At b128 lane-distinct + readlane h (lane u)
    float w0 = 0.f, w1 = 0.f, w2 = 0.f, w3 = 0.f;
#pragma unroll
    for (int u4 = 0; u4 < 16; ++u4) {
        float4 av = *(const float4*)&At_s[lt * 64 + (swz(lt, u4) << 2)];
#define MIXSTEP(a, u)                                    \
        w0 += (a) * rlane(h0, (u));                      \
        w1 += (a) * rlane(h1, (u));                      \
        w2 += (a) * rlane(h2, (u));                      \
        w3 += (a) * rlane(h3, (u));
        MIXSTEP(av.x, u4 * 4 + 0)
        MIXSTEP(av.y, u4 * 4 + 1)
        MIXSTEP(av.z, u4 * 4 + 2)
        MIXSTEP(av.w, u4 * 4 + 3)
    }
    float4 uo, po;
    uo.x = s1v * h0 + s3v * w0;  po.x = s0v * h0 + s2v * w0;
    uo.y = s1v * h1 + s3v * w1;  po.y = s0v * h1 + s2v * w1;
    uo.z = s1v * h2 + s3v * w2;  po.z = s0v * h2 + s2v * w2;
    uo.w = s1v * h3 + s3v * w3;  po.w = s0v * h3 + s2v * w3;
    size_t base = ((size_t)((b * 64 + lt) * 128 + n)) * 32 + fg * 4;
    *(float4*)(up + base) = uo;
    *(float4*)(pp + base) = po;
}

// ---------------------------------------------------------------------------
// Spatial kernel. grid = B*T*2 = 256, 512 threads.
// wave fg = tid>>6, lane m = tid&63 (local row of half mh; also slice slot:
// lane l holds up[n=2l..2l+1][fg-chunk] and Hsum[k=l&31][fg-chunk]).
// ---------------------------------------------------------------------------
template<bool LAST>
__global__ __launch_bounds__(512) void k_spatial(
    const float* __restrict__ up, const float* __restrict__ pp,
    const float* __restrict__ As, const float* __restrict__ H, int layer,
    const float* __restrict__ W2, const float* __restrict__ b2,
    float* __restrict__ hout, float* __restrict__ out)
{
    __shared__ float As_s[64 * 128];  // 32KB swizzled (b128 lane-distinct)
    __shared__ float Ah_s[64 * 32];   //  8KB swizzled
    __shared__ float T_s [64 * 32];   //  8KB swizzled (LAST only)

    const int tid = threadIdx.x;
    const int b   = blockIdx.x >> 7;
    const int t   = (blockIdx.x >> 1) & 63;
    const int mh  = blockIdx.x & 1;
    const int fg  = tid >> 6;
    const int m   = tid & 63;

    // stage As half-tile [64][128] swizzled
#pragma unroll
    for (int i = 0; i < 4; ++i) {
        int p = tid + 512 * i;
        int r = p >> 5, g = p & 31;
        float4 v = *(const float4*)(As + ((size_t)(mh * 64 + r)) * 128 + g * 4);
        *(float4*)&As_s[r * 128 + (swz(r, g) << 2)] = v;
    }
    // up register slice: lane l holds n=2l (ua) and n=2l+1 (ub)
    const float* urow = up + ((size_t)(b * 64 + t)) * 4096;
    float4 ua = *(const float4*)(urow + (2 * m)     * 32 + fg * 4);
    float4 ub = *(const float4*)(urow + (2 * m + 1) * 32 + fg * 4);
    // Hsum register slice: lane l holds k = l&31
    float4 hsr;
    {
        const float* Hl = H + layer * 4096 + (m & 31) * 32 + fg * 4;
        float4 q0 = *(const float4*)(Hl);
        float4 q1 = *(const float4*)(Hl + 1024);
        float4 q2 = *(const float4*)(Hl + 2048);
        float4 q3 = *(const float4*)(Hl + 3072);
        hsr.x = q0.x + q1.x + q2.x + q3.x;
        hsr.y = q0.y + q1.y + q2.y + q3.y;
        hsr.z = q0.z + q1.z + q2.z + q3.z;
        hsr.w = q0.w + q1.w + q2.w + q3.w;
    }
    // W2 slice (LAST): lane l holds W2[k=l&31][fo..fo+2]
    float2 w2r, b2v;
    if (LAST) {
        w2r = *(const float2*)(W2 + (m & 31) * 16 + fg * 2);
        b2v = *(const float2*)(b2 + fg * 2);
    }
    // acc init from pp
    float4 pv = *(const float4*)(pp + ((size_t)((b * 64 + t) * 128 + mh * 64 + m)) * 32 + fg * 4);
    float a0 = pv.x, a1 = pv.y, a2 = pv.z, a3 = pv.w;
    __syncthreads();

    // spatial mix: As b128 lane-distinct swizzled + readlane up
#pragma unroll
    for (int n4 = 0; n4 < 32; ++n4) {
        float4 av = *(const float4*)&As_s[m * 128 + (swz(m, n4) << 2)];
#define SPSTEP(a, reg, ln)                               \
        a0 += (a) * rlane(reg.x, (ln));                  \
        a1 += (a) * rlane(reg.y, (ln));                  \
        a2 += (a) * rlane(reg.z, (ln));                  \
        a3 += (a) * rlane(reg.w, (ln));
        SPSTEP(av.x, ua, 2 * n4)          // n = 4*n4   -> lane 2*n4, even
        SPSTEP(av.y, ub, 2 * n4)          // n = 4*n4+1 -> lane 2*n4, odd
        SPSTEP(av.z, ua, 2 * n4 + 1)      // n = 4*n4+2 -> lane 2*n4+1, even
        SPSTEP(av.w, ub, 2 * n4 + 1)      // n = 4*n4+3 -> lane 2*n4+1, odd
    }
    {
        float4 t4; t4.x = a0; t4.y = a1; t4.z = a2; t4.w = a3;
        *(float4*)&Ah_s[m * 32 + (swz(m, fg) << 2)] = t4;
    }
    __syncthreads();

    // graph filter + tanh: Ah b128 lane-distinct + readlane Hsum
    float c0 = 0.f, c1 = 0.f, c2 = 0.f, c3 = 0.f;
#pragma unroll
    for (int k4 = 0; k4 < 8; ++k4) {
        float4 av = *(const float4*)&Ah_s[m * 32 + (swz(m, k4) << 2)];
#define FSTEP(a, k)                                      \
        c0 += (a) * rlane(hsr.x, (k));                   \
        c1 += (a) * rlane(hsr.y, (k));                   \
        c2 += (a) * rlane(hsr.z, (k));                   \
        c3 += (a) * rlane(hsr.w, (k));
        FSTEP(av.x, k4 * 4 + 0)
        FSTEP(av.y, k4 * 4 + 1)
        FSTEP(av.z, k4 * 4 + 2)
        FSTEP(av.w, k4 * 4 + 3)
    }
    c0 = tanhf(c0); c1 = tanhf(c1); c2 = tanhf(c2); c3 = tanhf(c3);

    if (!LAST) {
        float4 o; o.x = c0; o.y = c1; o.z = c2; o.w = c3;
        // h stored n-major: [b][nglob][t][f]
        *(float4*)(hout + (((size_t)(b * 128 + mh * 64 + m)) * 64 + t) * 32 + fg * 4) = o;
    } else {
        float4 t4; t4.x = c0; t4.y = c1; t4.z = c2; t4.w = c3;
        *(float4*)&T_s[m * 32 + (swz(m, fg) << 2)] = t4;
        __syncthreads();
        // fused output projection: wave fg covers fo = {fg*2, fg*2+1}
        float o0 = b2v.x, o1 = b2v.y;
#pragma unroll
        for (int k4 = 0; k4 < 8; ++k4) {
            float4 tv = *(const float4*)&T_s[m * 32 + (swz(m, k4) << 2)];
#define OSTEP(a, k)                                      \
            o0 += (a) * rlane(w2r.x, (k));               \
            o1 += (a) * rlane(w2r.y, (k));
            OSTEP(tv.x, k4 * 4 + 0)
            OSTEP(tv.y, k4 * 4 + 1)
            OSTEP(tv.z, k4 * 4 + 2)
            OSTEP(tv.w, k4 * 4 + 3)
        }
        float2 o2; o2.x = o0; o2.y = o1;
        *(float2*)(out + ((size_t)((b * 64 + t) * 128 + mh * 64 + m)) * 16 + fg * 2) = o2;
    }
}

// ---------------------------------------------------------------------------
extern "C" void kernel_launch(void* const* d_in, const int* in_sizes, int n_in,
                              void* d_out, int out_size, void* d_ws, size_t ws_size,
                              hipStream_t stream)
{
    const float* x   = (const float*)d_in[0];
    const float* At  = (const float*)d_in[1];
    const float* As  = (const float*)d_in[2];
    const float* s   = (const float*)d_in[3];
    const float* H   = (const float*)d_in[4];
    const float* W1  = (const float*)d_in[5];
    const float* b1  = (const float*)d_in[6];
    const float* W2  = (const float*)d_in[7];
    const float* b2  = (const float*)d_in[8];
    float* out = (float*)d_out;

    float* up   = (float*)d_ws;            // [2][64][128][32]  524288 floats
    float* pp   = up + 524288;             // same layout
    float* hbuf = pp + 524288;             // [2][128][64][32]  n-major

    k_temporal<true ><<<256, 512, 0, stream>>>(x,    At, W1, b1, s, up, pp);
    k_spatial <false><<<256, 512, 0, stream>>>(up, pp, As, H, 0, W2, b2, hbuf, out);
    k_temporal<false><<<256, 512, 0, stream>>>(hbuf, At, W1, b1, s, up, pp);
    k_spatial <true ><<<256, 512, 0, stream>>>(up, pp, As, H, 1, W2, b2, hbuf, out);
}